// Round 1
// baseline (2639.309 us; speedup 1.0000x reference)
//
#include <hip/hip_runtime.h>
#include <cstdint>
#include <cstddef>

#define DIN 128
#define HID 256
#define MODD 500
#define OUTD 100

// ---------------- degree / CSR build ----------------

__global__ void count_deg(const int* __restrict__ dst, int* __restrict__ deg, int E) {
    int e = blockIdx.x * blockDim.x + threadIdx.x;
    if (e < E) atomicAdd(&deg[dst[e]], 1);
}

__global__ void compute_dinv(const int* __restrict__ deg, float* __restrict__ dinv, int N) {
    int i = blockIdx.x * blockDim.x + threadIdx.x;
    if (i < N) dinv[i] = rsqrtf((float)deg[i] + 2.0f);
}

// single-block exclusive scan of deg -> row_ptr (n up to a few hundred k is fine)
__global__ void scan_deg(const int* __restrict__ deg, int* __restrict__ row_ptr, int n) {
    __shared__ int wsum[16];
    __shared__ int carry_s;
    __shared__ int total_s;
    int tid = threadIdx.x;
    int lane = tid & 63;
    int w = tid >> 6;
    if (tid == 0) carry_s = 0;
    __syncthreads();
    for (int base = 0; base < n; base += 1024) {
        int i = base + tid;
        int v = (i < n) ? deg[i] : 0;
        int x = v;
        #pragma unroll
        for (int off = 1; off < 64; off <<= 1) {
            int t = __shfl_up(x, off);
            if (lane >= off) x += t;
        }
        if (lane == 63) wsum[w] = x;
        __syncthreads();
        if (tid == 0) {
            int s = 0;
            #pragma unroll
            for (int k = 0; k < 16; ++k) { int t = wsum[k]; wsum[k] = s; s += t; }
            total_s = s;
        }
        __syncthreads();
        if (i < n) row_ptr[i] = carry_s + wsum[w] + (x - v);
        __syncthreads();
        if (tid == 0) carry_s += total_s;
    }
    __syncthreads();
    if (tid == 0) row_ptr[n] = carry_s;
}

__global__ void init_cursor(const int* __restrict__ row_ptr, int* __restrict__ cur, int N) {
    int i = blockIdx.x * blockDim.x + threadIdx.x;
    if (i < N) cur[i] = row_ptr[i];
}

__global__ void scatter_edges(const int* __restrict__ src, const int* __restrict__ dst,
                              int* __restrict__ cur, int* __restrict__ col, int E) {
    int e = blockIdx.x * blockDim.x + threadIdx.x;
    if (e < E) {
        int d = dst[e];
        int p = atomicAdd(&cur[d], 1);
        col[p] = src[e];
    }
}

// ---------------- aggregation (gather over CSR) ----------------
// Y[n] = 2*dinv[n]^2 * X[n] + sum_{e in in(n)} dinv[src]*dinv[n] * X[src]

// D = 128: one wave per node, float2 per lane
__global__ void aggregate128(const float* __restrict__ X, float* __restrict__ Y,
                             const int* __restrict__ rp, const int* __restrict__ col,
                             const float* __restrict__ dinv, int N) {
    int gw = blockIdx.x * (blockDim.x >> 6) + (threadIdx.x >> 6);
    int lane = threadIdx.x & 63;
    if (gw >= N) return;
    float di = dinv[gw];
    float sc = 2.0f * di * di;
    const float2* Xr = (const float2*)X;
    float2 s = Xr[(size_t)gw * 64 + lane];
    float2 acc;
    acc.x = sc * s.x;
    acc.y = sc * s.y;
    int e = rp[gw], end = rp[gw + 1];
    for (; e < end; ++e) {
        int c = col[e];
        float cw = dinv[c] * di;
        float2 v = Xr[(size_t)c * 64 + lane];
        acc.x += cw * v.x;
        acc.y += cw * v.y;
    }
    ((float2*)Y)[(size_t)gw * 64 + lane] = acc;
}

// D = 256: one wave per node, float4 per lane
__global__ void aggregate256(const float* __restrict__ X, float* __restrict__ Y,
                             const int* __restrict__ rp, const int* __restrict__ col,
                             const float* __restrict__ dinv, int N) {
    int gw = blockIdx.x * (blockDim.x >> 6) + (threadIdx.x >> 6);
    int lane = threadIdx.x & 63;
    if (gw >= N) return;
    float di = dinv[gw];
    float sc = 2.0f * di * di;
    const float4* Xr = (const float4*)X;
    float4 s = Xr[(size_t)gw * 64 + lane];
    float4 acc;
    acc.x = sc * s.x; acc.y = sc * s.y; acc.z = sc * s.z; acc.w = sc * s.w;
    int e = rp[gw], end = rp[gw + 1];
    for (; e < end; ++e) {
        int c = col[e];
        float cw = dinv[c] * di;
        float4 v = Xr[(size_t)c * 64 + lane];
        acc.x += cw * v.x; acc.y += cw * v.y; acc.z += cw * v.z; acc.w += cw * v.w;
    }
    ((float4*)Y)[(size_t)gw * 64 + lane] = acc;
}

// ---------------- fp32 tiled GEMM with fused epilogue ----------------
// C[M,N] = epi(A[M,K] @ B[K,N] + bias), row-major, lda=K, ldb=N, ldc=N.
// EPI: 0 = relu, 1 = softplus, 2 = none. TANH_A: apply tanh(sp * a) on A load.

#define BM 64
#define BN 64
#define BK 16

template<int EPI, bool TANH_A>
__global__ __launch_bounds__(256)
void gemm_epi(const float* __restrict__ A, const float* __restrict__ B,
              const float* __restrict__ bias, float* __restrict__ C,
              int M, int N, int K, const float* __restrict__ thr_ptr) {
    __shared__ __align__(16) float sA[BK][BM + 4];
    __shared__ __align__(16) float sB[BK][BN + 4];
    int tid = threadIdx.x;
    int tx = tid & 15;        // col group
    int ty = tid >> 4;        // row group
    int row0 = blockIdx.y * BM;
    int col0 = blockIdx.x * BN;
    float acc[4][4] = {};
    float sp = 1.0f;
    if (TANH_A) {
        float t = *thr_ptr;
        sp = (t > 20.0f) ? t : log1pf(expf(t));
    }

    for (int kt = 0; kt < K; kt += BK) {
        #pragma unroll
        for (int i = 0; i < 4; ++i) {
            int idx = tid + i * 256;
            int r = idx >> 4;
            int kk = idx & 15;
            int gr = row0 + r, gk = kt + kk;
            float v = 0.0f;
            if (gr < M && gk < K) v = A[(size_t)gr * K + gk];
            if (TANH_A) v = tanhf(sp * v);
            sA[kk][r] = v;
        }
        #pragma unroll
        for (int i = 0; i < 4; ++i) {
            int idx = tid + i * 256;
            int kk = idx >> 6;
            int c = idx & 63;
            int gk = kt + kk, gc = col0 + c;
            float v = 0.0f;
            if (gk < K && gc < N) v = B[(size_t)gk * N + gc];
            sB[kk][c] = v;
        }
        __syncthreads();
        #pragma unroll
        for (int kk = 0; kk < BK; ++kk) {
            float4 a4 = *(const float4*)&sA[kk][ty * 4];
            float4 b4 = *(const float4*)&sB[kk][tx * 4];
            float a[4] = {a4.x, a4.y, a4.z, a4.w};
            float b[4] = {b4.x, b4.y, b4.z, b4.w};
            #pragma unroll
            for (int i = 0; i < 4; ++i)
                #pragma unroll
                for (int j = 0; j < 4; ++j)
                    acc[i][j] += a[i] * b[j];
        }
        __syncthreads();
    }

    #pragma unroll
    for (int i = 0; i < 4; ++i) {
        int gr = row0 + ty * 4 + i;
        if (gr >= M) continue;
        #pragma unroll
        for (int j = 0; j < 4; ++j) {
            int gc = col0 + tx * 4 + j;
            if (gc >= N) continue;
            float v = acc[i][j] + bias[gc];
            if (EPI == 0) v = fmaxf(v, 0.0f);
            else if (EPI == 1) v = (v > 20.0f) ? v : log1pf(expf(v));
            C[(size_t)gr * N + gc] = v;
        }
    }
}

// ---------------- launch ----------------

extern "C" void kernel_launch(void* const* d_in, const int* in_sizes, int n_in,
                              void* d_out, int out_size, void* d_ws, size_t ws_size,
                              hipStream_t stream) {
    const float* x    = (const float*)d_in[0];
    const int*   ei   = (const int*)d_in[1];
    const float* W1   = (const float*)d_in[2];
    const float* b1   = (const float*)d_in[3];
    const float* W2   = (const float*)d_in[4];
    const float* b2   = (const float*)d_in[5];
    const float* Wout = (const float*)d_in[6];
    const float* bout = (const float*)d_in[7];
    const float* thr  = (const float*)d_in[8];

    int N = in_sizes[0] / DIN;
    int E = in_sizes[1] / 2;
    const int* srcI = ei;
    const int* dstI = ei + E;

    char* wsp = (char*)d_ws;
    size_t o = 0;
    auto alloc = [&](size_t bytes) -> void* {
        void* p = wsp + o;
        o = (o + bytes + 255) & ~(size_t)255;
        return p;
    };
    int*   deg  = (int*)alloc((size_t)N * 4);
    float* dinv = (float*)alloc((size_t)N * 4);
    int*   rp   = (int*)alloc((size_t)(N + 1) * 4);
    int*   cur  = (int*)alloc((size_t)N * 4);
    int*   col  = (int*)alloc((size_t)E * 4);
    float* bufA = (float*)alloc((size_t)N * HID * 4);  // xa (N*128) then ha (N*256)
    float* hbuf = (float*)alloc((size_t)N * HID * 4);  // h (N*256)

    float* mr   = (float*)d_out;                        // [N, 500]
    float* yout = (float*)d_out + (size_t)N * MODD;     // [N, 100]

    hipMemsetAsync(deg, 0, (size_t)N * 4, stream);
    count_deg<<<(E + 255) / 256, 256, 0, stream>>>(dstI, deg, E);
    compute_dinv<<<(N + 255) / 256, 256, 0, stream>>>(deg, dinv, N);
    scan_deg<<<1, 1024, 0, stream>>>(deg, rp, N);
    init_cursor<<<(N + 255) / 256, 256, 0, stream>>>(rp, cur, N);
    scatter_edges<<<(E + 255) / 256, 256, 0, stream>>>(srcI, dstI, cur, col, E);

    // conv1: xa = aggregate(x); h = relu(xa @ W1 + b1)
    aggregate128<<<(N + 3) / 4, 256, 0, stream>>>(x, bufA, rp, col, dinv, N);
    dim3 g1((HID + BN - 1) / BN, (N + BM - 1) / BM);
    gemm_epi<0, false><<<g1, 256, 0, stream>>>(bufA, W1, b1, hbuf, N, HID, DIN, nullptr);

    // conv2: ha = aggregate(h); mr = softplus(ha @ W2 + b2)
    aggregate256<<<(N + 3) / 4, 256, 0, stream>>>(hbuf, bufA, rp, col, dinv, N);
    dim3 g2((MODD + BN - 1) / BN, (N + BM - 1) / BM);
    gemm_epi<1, false><<<g2, 256, 0, stream>>>(bufA, W2, b2, mr, N, MODD, HID, nullptr);

    // head: y = tanh(sp * mr) @ Wout + bout
    dim3 g3((OUTD + BN - 1) / BN, (N + BM - 1) / BM);
    gemm_epi<2, true><<<g3, 256, 0, stream>>>(mr, Wout, bout, yout, N, OUTD, MODD, thr);
}

// Round 2
// 1427.279 us; speedup vs baseline: 1.8492x; 1.8492x over previous
//
#include <hip/hip_runtime.h>
#include <cstdint>
#include <cstddef>

#define DIN 128
#define HID 256
#define MODD 500
#define OUTD 100

typedef unsigned int uint;
typedef unsigned short ushort;
typedef __attribute__((ext_vector_type(8))) __bf16 bf16x8;
typedef __attribute__((ext_vector_type(4))) float f32x4;

__device__ __forceinline__ float bf2f(ushort u) {
    return __uint_as_float(((uint)u) << 16);
}
__device__ __forceinline__ ushort f2bf(float f) {
    uint u = __float_as_uint(f);
    return (ushort)((u + 0x7FFF + ((u >> 16) & 1)) >> 16);
}
__device__ __forceinline__ void async_copy16(const void* g, void* l) {
    __builtin_amdgcn_global_load_lds((const __attribute__((address_space(1))) void*)g,
                                     (__attribute__((address_space(3))) void*)l, 16, 0, 0);
}
__device__ __forceinline__ float tanh_fast(float x) {
    // x >= 0 in our use (softplus output); stable both ends anyway
    return 1.0f - 2.0f / (__expf(2.0f * x) + 1.0f);
}

// ---------------- degree / CSR build ----------------

__global__ void count_deg(const int* __restrict__ dst, int* __restrict__ deg, int E) {
    int e = blockIdx.x * blockDim.x + threadIdx.x;
    if (e < E) atomicAdd(&deg[dst[e]], 1);
}

__global__ void compute_dinv(const int* __restrict__ deg, float* __restrict__ dinv, int N) {
    int i = blockIdx.x * blockDim.x + threadIdx.x;
    if (i < N) dinv[i] = rsqrtf((float)deg[i] + 2.0f);
}

// 3-phase scan: per-block scan -> scan of block sums -> add offsets
__global__ void scan_block(const int* __restrict__ deg, int* __restrict__ rp,
                           int* __restrict__ bsum, int n) {
    __shared__ int wsum[16];
    int tid = threadIdx.x;
    int lane = tid & 63;
    int w = tid >> 6;
    int i = blockIdx.x * 1024 + tid;
    int v = (i < n) ? deg[i] : 0;
    int x = v;
    #pragma unroll
    for (int off = 1; off < 64; off <<= 1) {
        int t = __shfl_up(x, off);
        if (lane >= off) x += t;
    }
    if (lane == 63) wsum[w] = x;
    __syncthreads();
    if (tid == 0) {
        int s = 0;
        #pragma unroll
        for (int k = 0; k < 16; ++k) { int t = wsum[k]; wsum[k] = s; s += t; }
        bsum[blockIdx.x] = s;
    }
    __syncthreads();
    if (i < n) rp[i] = wsum[w] + (x - v);
}

__global__ void scan_bsums(int* __restrict__ bsum, int nb) {
    if (threadIdx.x == 0 && blockIdx.x == 0) {
        int s = 0;
        for (int k = 0; k < nb; ++k) { int t = bsum[k]; bsum[k] = s; s += t; }
        bsum[nb] = s;
    }
}

__global__ void scan_add(int* __restrict__ rp, const int* __restrict__ bsum, int n, int nb) {
    int i = blockIdx.x * blockDim.x + threadIdx.x;
    if (i < n) rp[i] += bsum[i >> 10];
    else if (i == n) rp[n] = bsum[nb];
}

__global__ void init_cursor(const int* __restrict__ row_ptr, int* __restrict__ cur, int N) {
    int i = blockIdx.x * blockDim.x + threadIdx.x;
    if (i < N) cur[i] = row_ptr[i];
}

__global__ void scatter_edges(const int* __restrict__ src, const int* __restrict__ dst,
                              int* __restrict__ cur, int* __restrict__ col, int E) {
    int e = blockIdx.x * blockDim.x + threadIdx.x;
    if (e < E) {
        int d = dst[e];
        int p = atomicAdd(&cur[d], 1);
        col[p] = src[e];
    }
}

// ---------------- casts / transposes ----------------

__global__ void cast_f32_bf16(const float* __restrict__ src, ushort* __restrict__ dst, int n4) {
    int i = blockIdx.x * blockDim.x + threadIdx.x;
    if (i < n4) {
        float4 v = ((const float4*)src)[i];
        ushort4 o;
        o.x = f2bf(v.x); o.y = f2bf(v.y); o.z = f2bf(v.z); o.w = f2bf(v.w);
        ((ushort4*)dst)[i] = o;
    }
}

// src[K][N] fp32 -> dst[Npad][Kpad] bf16 (zero padded)
__global__ void transpose_cast(const float* __restrict__ src, ushort* __restrict__ dst,
                               int K, int N, int Kpad, int Npad) {
    int idx = blockIdx.x * blockDim.x + threadIdx.x;
    if (idx >= Npad * Kpad) return;
    int n = idx / Kpad, k = idx - n * Kpad;
    float v = (n < N && k < K) ? src[(size_t)k * N + n] : 0.0f;
    dst[idx] = f2bf(v);
}

// ---------------- aggregation (gather over CSR, bf16 rows, fp32 accum) ----------------
// Y[n] = 2*dinv[n]^2 * X[n] + sum_{e in in(n)} dinv[src]*dinv[n] * X[src]

// D = 128 bf16: one wave/node, uint (2 bf16) per lane
__global__ void aggregate128(const ushort* __restrict__ X, ushort* __restrict__ Y,
                             const int* __restrict__ rp, const int* __restrict__ col,
                             const float* __restrict__ dinv, int N) {
    int gw = blockIdx.x * (blockDim.x >> 6) + (threadIdx.x >> 6);
    int lane = threadIdx.x & 63;
    if (gw >= N) return;
    float di = dinv[gw];
    float sc = 2.0f * di * di;
    const uint* Xr = (const uint*)X;
    uint s = Xr[(size_t)gw * 64 + lane];
    float ax = sc * bf2f((ushort)(s & 0xFFFF));
    float ay = sc * bf2f((ushort)(s >> 16));
    int e = rp[gw], end = rp[gw + 1];
    for (; e + 2 <= end; e += 2) {
        int c0 = col[e], c1 = col[e + 1];
        float w0 = dinv[c0] * di, w1 = dinv[c1] * di;
        uint v0 = Xr[(size_t)c0 * 64 + lane];
        uint v1 = Xr[(size_t)c1 * 64 + lane];
        ax += w0 * bf2f((ushort)(v0 & 0xFFFF));
        ay += w0 * bf2f((ushort)(v0 >> 16));
        ax += w1 * bf2f((ushort)(v1 & 0xFFFF));
        ay += w1 * bf2f((ushort)(v1 >> 16));
    }
    if (e < end) {
        int c0 = col[e];
        float w0 = dinv[c0] * di;
        uint v0 = Xr[(size_t)c0 * 64 + lane];
        ax += w0 * bf2f((ushort)(v0 & 0xFFFF));
        ay += w0 * bf2f((ushort)(v0 >> 16));
    }
    uint out = (uint)f2bf(ax) | ((uint)f2bf(ay) << 16);
    ((uint*)Y)[(size_t)gw * 64 + lane] = out;
}

// D = 256 bf16: one wave/node, uint2 (4 bf16) per lane
__global__ void aggregate256(const ushort* __restrict__ X, ushort* __restrict__ Y,
                             const int* __restrict__ rp, const int* __restrict__ col,
                             const float* __restrict__ dinv, int N) {
    int gw = blockIdx.x * (blockDim.x >> 6) + (threadIdx.x >> 6);
    int lane = threadIdx.x & 63;
    if (gw >= N) return;
    float di = dinv[gw];
    float sc = 2.0f * di * di;
    const uint2* Xr = (const uint2*)X;
    uint2 s = Xr[(size_t)gw * 64 + lane];
    float a0 = sc * bf2f((ushort)(s.x & 0xFFFF));
    float a1 = sc * bf2f((ushort)(s.x >> 16));
    float a2 = sc * bf2f((ushort)(s.y & 0xFFFF));
    float a3 = sc * bf2f((ushort)(s.y >> 16));
    int e = rp[gw], end = rp[gw + 1];
    for (; e + 2 <= end; e += 2) {
        int c0 = col[e], c1 = col[e + 1];
        float w0 = dinv[c0] * di, w1 = dinv[c1] * di;
        uint2 v0 = Xr[(size_t)c0 * 64 + lane];
        uint2 v1 = Xr[(size_t)c1 * 64 + lane];
        a0 += w0 * bf2f((ushort)(v0.x & 0xFFFF));
        a1 += w0 * bf2f((ushort)(v0.x >> 16));
        a2 += w0 * bf2f((ushort)(v0.y & 0xFFFF));
        a3 += w0 * bf2f((ushort)(v0.y >> 16));
        a0 += w1 * bf2f((ushort)(v1.x & 0xFFFF));
        a1 += w1 * bf2f((ushort)(v1.x >> 16));
        a2 += w1 * bf2f((ushort)(v1.y & 0xFFFF));
        a3 += w1 * bf2f((ushort)(v1.y >> 16));
    }
    if (e < end) {
        int c0 = col[e];
        float w0 = dinv[c0] * di;
        uint2 v0 = Xr[(size_t)c0 * 64 + lane];
        a0 += w0 * bf2f((ushort)(v0.x & 0xFFFF));
        a1 += w0 * bf2f((ushort)(v0.x >> 16));
        a2 += w0 * bf2f((ushort)(v0.y & 0xFFFF));
        a3 += w0 * bf2f((ushort)(v0.y >> 16));
    }
    uint2 out;
    out.x = (uint)f2bf(a0) | ((uint)f2bf(a1) << 16);
    out.y = (uint)f2bf(a2) | ((uint)f2bf(a3) << 16);
    ((uint2*)Y)[(size_t)gw * 64 + lane] = out;
}

// ---------------- bf16 MFMA GEMM (m97 structure) ----------------
// C[M,Nact] = epi(A[M,K]_bf16 @ BT[Npad,K]_bf16^T + bias)
// BM=128, BN=128, BK=32, 256 threads = 4 waves, each wave 64x64 (4x4 MFMA tiles)
// MODE 0: relu -> bf16 store; MODE 1: softplus -> f32 store; MODE 2: plain -> f32 store

template<int K, int MODE>
__global__ __launch_bounds__(256)
void gemm_bt(const ushort* __restrict__ A, const ushort* __restrict__ BT,
             const float* __restrict__ bias, void* __restrict__ Cout,
             int M, int Nact, int ldc) {
    __shared__ ushort sA[128 * 32];
    __shared__ ushort sB[128 * 32];
    int tid = threadIdx.x;
    int lane = tid & 63;
    int w = tid >> 6;
    int wr = w >> 1, wc = w & 1;
    int row0 = blockIdx.y * 128;
    int col0 = blockIdx.x * 128;
    f32x4 acc[4][4] = {};

    for (int kt = 0; kt < K; kt += 32) {
        if (kt) __syncthreads();
        #pragma unroll
        for (int L = 0; L < 2; ++L) {
            int cb = L * 256 + w * 64;
            int c = cb + lane;
            int r = c >> 2;
            int ko = (c & 3) * 8;
            int rr = min(row0 + r, M - 1);
            async_copy16(A + (size_t)rr * K + kt + ko, sA + (size_t)cb * 8);
        }
        #pragma unroll
        for (int L = 0; L < 2; ++L) {
            int cb = L * 256 + w * 64;
            int c = cb + lane;
            int nr = c >> 2;
            int ko = (c & 3) * 8;
            async_copy16(BT + (size_t)(col0 + nr) * K + kt + ko, sB + (size_t)cb * 8);
        }
        __syncthreads();
        bf16x8 af[4], bfr[4];
        #pragma unroll
        for (int i = 0; i < 4; ++i) {
            int row = wr * 64 + i * 16 + (lane & 15);
            af[i] = *(const bf16x8*)(sA + row * 32 + (lane >> 4) * 8);
        }
        #pragma unroll
        for (int j = 0; j < 4; ++j) {
            int n = wc * 64 + j * 16 + (lane & 15);
            bfr[j] = *(const bf16x8*)(sB + n * 32 + (lane >> 4) * 8);
        }
        #pragma unroll
        for (int i = 0; i < 4; ++i)
            #pragma unroll
            for (int j = 0; j < 4; ++j)
                acc[i][j] = __builtin_amdgcn_mfma_f32_16x16x32_bf16(af[i], bfr[j], acc[i][j], 0, 0, 0);
    }

    #pragma unroll
    for (int i = 0; i < 4; ++i) {
        #pragma unroll
        for (int j = 0; j < 4; ++j) {
            int col = col0 + wc * 64 + j * 16 + (lane & 15);
            if (col >= Nact) continue;
            float bv = bias[col];
            #pragma unroll
            for (int r = 0; r < 4; ++r) {
                int row = row0 + wr * 64 + i * 16 + (lane >> 4) * 4 + r;
                if (row >= M) continue;
                float v = acc[i][j][r] + bv;
                if (MODE == 0) {
                    v = fmaxf(v, 0.0f);
                    ((ushort*)Cout)[(size_t)row * ldc + col] = f2bf(v);
                } else if (MODE == 1) {
                    v = (v > 20.0f) ? v : log1pf(expf(v));
                    ((float*)Cout)[(size_t)row * ldc + col] = v;
                } else {
                    ((float*)Cout)[(size_t)row * ldc + col] = v;
                }
            }
        }
    }
}

// GEMM3: A = tanh(sp * mr) computed on the fly from fp32 mr[M,500]; K padded to 512.
__global__ __launch_bounds__(256)
void gemm_tanh(const float* __restrict__ Ain, const ushort* __restrict__ BT,
               const float* __restrict__ bias, float* __restrict__ Cout,
               int M, int Nact, int ldc, const float* __restrict__ thr) {
    const int K = 512, KA = 500;
    __shared__ ushort sA[128 * 32];
    __shared__ ushort sB[128 * 32];
    int tid = threadIdx.x;
    int lane = tid & 63;
    int w = tid >> 6;
    int wr = w >> 1, wc = w & 1;
    int row0 = blockIdx.y * 128;
    int col0 = blockIdx.x * 128;
    float t = *thr;
    float sp = (t > 20.0f) ? t : log1pf(expf(t));
    f32x4 acc[4][4] = {};

    int r = tid >> 1;
    int kh = (tid & 1) * 16;
    int rr_a = min(row0 + r, M - 1);
    const float* arow = Ain + (size_t)rr_a * KA;

    for (int kt = 0; kt < K; kt += 32) {
        if (kt) __syncthreads();
        // A: manual stage with fused tanh + cast
        float vals[16];
        int kb = kt + kh;
        if (kb + 16 <= KA) {
            #pragma unroll
            for (int q = 0; q < 4; ++q) {
                float4 f = *(const float4*)(arow + kb + q * 4);
                vals[q * 4 + 0] = f.x; vals[q * 4 + 1] = f.y;
                vals[q * 4 + 2] = f.z; vals[q * 4 + 3] = f.w;
            }
        } else {
            #pragma unroll
            for (int q = 0; q < 16; ++q) {
                int k = kb + q;
                vals[q] = (k < KA) ? arow[k] : 0.0f;
            }
        }
        ushort us[16];
        #pragma unroll
        for (int q = 0; q < 16; ++q) us[q] = f2bf(tanh_fast(sp * vals[q]));
        *(uint4*)(sA + r * 32 + kh) = *(const uint4*)(us);
        *(uint4*)(sA + r * 32 + kh + 8) = *(const uint4*)(us + 8);
        // B: async stage
        #pragma unroll
        for (int L = 0; L < 2; ++L) {
            int cb = L * 256 + w * 64;
            int c = cb + lane;
            int nr = c >> 2;
            int ko = (c & 3) * 8;
            async_copy16(BT + (size_t)(col0 + nr) * K + kt + ko, sB + (size_t)cb * 8);
        }
        __syncthreads();
        bf16x8 af[4], bfr[4];
        #pragma unroll
        for (int i = 0; i < 4; ++i) {
            int row = wr * 64 + i * 16 + (lane & 15);
            af[i] = *(const bf16x8*)(sA + row * 32 + (lane >> 4) * 8);
        }
        #pragma unroll
        for (int j = 0; j < 4; ++j) {
            int n = wc * 64 + j * 16 + (lane & 15);
            bfr[j] = *(const bf16x8*)(sB + n * 32 + (lane >> 4) * 8);
        }
        #pragma unroll
        for (int i = 0; i < 4; ++i)
            #pragma unroll
            for (int j = 0; j < 4; ++j)
                acc[i][j] = __builtin_amdgcn_mfma_f32_16x16x32_bf16(af[i], bfr[j], acc[i][j], 0, 0, 0);
    }

    #pragma unroll
    for (int i = 0; i < 4; ++i) {
        #pragma unroll
        for (int j = 0; j < 4; ++j) {
            int col = col0 + wc * 64 + j * 16 + (lane & 15);
            if (col >= Nact) continue;
            float bv = bias[col];
            #pragma unroll
            for (int rix = 0; rix < 4; ++rix) {
                int row = row0 + wr * 64 + i * 16 + (lane >> 4) * 4 + rix;
                if (row >= M) continue;
                Cout[(size_t)row * ldc + col] = acc[i][j][rix] + bv;
            }
        }
    }
}

// ---------------- launch ----------------

extern "C" void kernel_launch(void* const* d_in, const int* in_sizes, int n_in,
                              void* d_out, int out_size, void* d_ws, size_t ws_size,
                              hipStream_t stream) {
    const float* x    = (const float*)d_in[0];
    const int*   ei   = (const int*)d_in[1];
    const float* W1   = (const float*)d_in[2];
    const float* b1   = (const float*)d_in[3];
    const float* W2   = (const float*)d_in[4];
    const float* b2   = (const float*)d_in[5];
    const float* Wout = (const float*)d_in[6];
    const float* bout = (const float*)d_in[7];
    const float* thr  = (const float*)d_in[8];

    int N = in_sizes[0] / DIN;
    int E = in_sizes[1] / 2;
    const int* srcI = ei;
    const int* dstI = ei + E;

    char* wsp = (char*)d_ws;
    size_t o = 0;
    auto alloc = [&](size_t bytes) -> void* {
        void* p = wsp + o;
        o = (o + bytes + 255) & ~(size_t)255;
        return p;
    };
    int*    deg   = (int*)alloc((size_t)N * 4);
    float*  dinv  = (float*)alloc((size_t)N * 4);
    int*    rp    = (int*)alloc((size_t)(N + 1) * 4);
    int*    cur   = (int*)alloc((size_t)N * 4);
    int*    bsum  = (int*)alloc(1024);
    int*    col   = (int*)alloc((size_t)E * 4);
    ushort* W1T   = (ushort*)alloc((size_t)256 * 128 * 2);
    ushort* W2T   = (ushort*)alloc((size_t)512 * 256 * 2);
    ushort* WoutT = (ushort*)alloc((size_t)128 * 512 * 2);
    ushort* bufA  = (ushort*)alloc((size_t)N * 256 * 2);  // xbf+xa, later ha
    ushort* hbuf  = (ushort*)alloc((size_t)N * 256 * 2);  // h bf16

    ushort* xbf = bufA;                       // [N,128] bf16
    ushort* xa  = bufA + (size_t)N * 128;     // [N,128] bf16
    ushort* ha  = bufA;                       // [N,256] bf16 (reuses xbf+xa)

    float* mr   = (float*)d_out;                    // [N,500]
    float* yout = (float*)d_out + (size_t)N * MODD; // [N,100]

    int mtiles = (N + 127) / 128;

    // --- CSR build ---
    hipMemsetAsync(deg, 0, (size_t)N * 4, stream);
    count_deg<<<(E + 255) / 256, 256, 0, stream>>>(dstI, deg, E);
    compute_dinv<<<(N + 255) / 256, 256, 0, stream>>>(deg, dinv, N);
    int nb = (N + 1023) / 1024;
    scan_block<<<nb, 1024, 0, stream>>>(deg, rp, bsum, N);
    scan_bsums<<<1, 64, 0, stream>>>(bsum, nb);
    scan_add<<<(N + 256) / 256, 256, 0, stream>>>(rp, bsum, N, nb);
    init_cursor<<<(N + 255) / 256, 256, 0, stream>>>(rp, cur, N);
    scatter_edges<<<(E + 255) / 256, 256, 0, stream>>>(srcI, dstI, cur, col, E);

    // --- weight prep ---
    cast_f32_bf16<<<((N * DIN / 4) + 255) / 256, 256, 0, stream>>>(x, xbf, N * DIN / 4);
    transpose_cast<<<(256 * 128 + 255) / 256, 256, 0, stream>>>(W1, W1T, 128, 256, 128, 256);
    transpose_cast<<<(512 * 256 + 255) / 256, 256, 0, stream>>>(W2, W2T, 256, 500, 256, 512);
    transpose_cast<<<(128 * 512 + 255) / 256, 256, 0, stream>>>(Wout, WoutT, 500, 100, 512, 128);

    // --- conv1 ---
    aggregate128<<<(N + 3) / 4, 256, 0, stream>>>(xbf, xa, rp, col, dinv, N);
    gemm_bt<128, 0><<<dim3(2, mtiles), 256, 0, stream>>>(xa, W1T, b1, hbuf, N, HID, HID);

    // --- conv2 ---
    aggregate256<<<(N + 3) / 4, 256, 0, stream>>>(hbuf, ha, rp, col, dinv, N);
    gemm_bt<256, 1><<<dim3(4, mtiles), 256, 0, stream>>>(ha, W2T, b2, mr, N, MODD, MODD);

    // --- head: y = tanh(sp*mr) @ Wout + bout ---
    gemm_tanh<<<dim3(1, mtiles), 256, 0, stream>>>(mr, WoutT, bout, yout, N, OUTD, OUTD, thr);
}